// Round 6
// baseline (382.669 us; speedup 1.0000x reference)
//
#include <hip/hip_runtime.h>

typedef unsigned int uint;
typedef unsigned short ushort;
typedef __attribute__((ext_vector_type(2))) uint  u32x2;
typedef __attribute__((ext_vector_type(4))) short s16x4;
typedef __attribute__((ext_vector_type(4))) float f32x4;

#if __has_builtin(__builtin_amdgcn_mfma_f32_16x16x16bf16_1k)
#define MFMA(a,b,c) __builtin_amdgcn_mfma_f32_16x16x16bf16_1k((a),(b),(c),0,0,0)
#else
__device__ __forceinline__ f32x4 mfma_fb(s16x4 a, s16x4 b, f32x4 c){
    asm volatile("v_mfma_f32_16x16x16_bf16 %0, %1, %2, %0\n\ts_nop 7\n\ts_nop 7"
                 : "+v"(c) : "v"(a), "v"(b));
    return c;
}
#define MFMA(a,b,c) mfma_fb((a),(b),(c))
#endif

__device__ __forceinline__ uint  fbits(float f){ return __builtin_bit_cast(uint, f); }
__device__ __forceinline__ float ibits(uint u){ return __builtin_bit_cast(float, u); }

// truncation split: x ~= hi + lo, both bf16 (error ~2^-17 rel; lo*lo dropped)
__device__ __forceinline__ void split4(f32x4 x, s16x4& hi, s16x4& lo){
    uint b0=fbits(x.x), b1=fbits(x.y), b2=fbits(x.z), b3=fbits(x.w);
    u32x2 h; h.x = (b0>>16) | (b1 & 0xFFFF0000u); h.y = (b2>>16) | (b3 & 0xFFFF0000u);
    float l0 = x.x - ibits(b0 & 0xFFFF0000u);
    float l1 = x.y - ibits(b1 & 0xFFFF0000u);
    float l2 = x.z - ibits(b2 & 0xFFFF0000u);
    float l3 = x.w - ibits(b3 & 0xFFFF0000u);
    u32x2 l; l.x = (fbits(l0)>>16) | (fbits(l1) & 0xFFFF0000u);
    l.y = (fbits(l2)>>16) | (fbits(l3) & 0xFFFF0000u);
    hi = __builtin_bit_cast(s16x4, h);
    lo = __builtin_bit_cast(s16x4, l);
}

// ---------------- weight packing into per-lane MFMA fragments ----------------
// uint2 units: [0..255] W1hi  [256..511] W1lo  [512..767] W2hi  [768..1023] W2lo
//   (index = t*64 + lane). Then floats at 2048+: b1 fragments, f32x4 per (t,lane).
__global__ void pack_weights(const float* __restrict__ W1, const float* __restrict__ b1,
                             const float* __restrict__ W2, float* __restrict__ ws)
{
    const int e = threadIdx.x;          // 256 = 4 tiles * 64 lanes
    const int t = e >> 6, l = e & 63;
    const int g = l >> 4, m = l & 15;

    float w1v[4], w2v[4];
    #pragma unroll
    for (int j = 0; j < 4; ++j) {
        w1v[j] = W1[(4*g + j)*64 + 16*t + m];
        w2v[j] = W2[(16*t + 4*g + j)*16 + m];
    }
    ushort h1[4], o1[4], h2[4], o2[4];
    #pragma unroll
    for (int j = 0; j < 4; ++j) {
        uint u1 = fbits(w1v[j]);
        ushort a = (ushort)((u1 + 0x7FFFu + ((u1>>16)&1u)) >> 16);      // RNE hi
        float  r = w1v[j] - ibits(((uint)a) << 16);
        uint ur = fbits(r);
        ushort b = (ushort)((ur + 0x7FFFu + ((ur>>16)&1u)) >> 16);      // RNE lo
        h1[j] = a; o1[j] = b;
        uint u2 = fbits(w2v[j]);
        a = (ushort)((u2 + 0x7FFFu + ((u2>>16)&1u)) >> 16);
        r = w2v[j] - ibits(((uint)a) << 16);
        ur = fbits(r);
        b = (ushort)((ur + 0x7FFFu + ((ur>>16)&1u)) >> 16);
        h2[j] = a; o2[j] = b;
    }
    u32x2* wp = (u32x2*)ws;
    u32x2 x;
    x.x = (uint)h1[0] | ((uint)h1[1] << 16); x.y = (uint)h1[2] | ((uint)h1[3] << 16);
    wp[e] = x;
    x.x = (uint)o1[0] | ((uint)o1[1] << 16); x.y = (uint)o1[2] | ((uint)o1[3] << 16);
    wp[256 + e] = x;
    x.x = (uint)h2[0] | ((uint)h2[1] << 16); x.y = (uint)h2[2] | ((uint)h2[3] << 16);
    wp[512 + e] = x;
    x.x = (uint)o2[0] | ((uint)o2[1] << 16); x.y = (uint)o2[2] | ((uint)o2[3] << 16);
    wp[768 + e] = x;

    f32x4 bb;
    bb.x = b1[16*t + 4*g + 0]; bb.y = b1[16*t + 4*g + 1];
    bb.z = b1[16*t + 4*g + 2]; bb.w = b1[16*t + 4*g + 3];
    ((f32x4*)(ws + 2048))[e] = bb;
}

// ---------------- main kernel ----------------
// One wave = 16 rows. Swapped-operand GEMMs make layer-1's C-fragment exactly
// layer-2's B-fragment (zero cross-lane movement). hi/lo bf16 split keeps fp32
// accuracy. ROUND 6 CHANGE: waves_per_eu(4,4) -> (8,8). VGPR live set is 52,
// so the 64-reg budget at 8 waves/EU fits with no spills; round 5's pin at 4
// waves/EU was the latency bottleneck (all pipes <41%).
__global__ __launch_bounds__(256) __attribute__((amdgpu_waves_per_eu(8, 8)))
void subattn_mfma(const float* __restrict__ q, const float* __restrict__ k,
                  const float* __restrict__ v, const float* __restrict__ pe,
                  const float* __restrict__ ws, float* __restrict__ out)
{
    const int tid = threadIdx.x;
    const int wv  = tid >> 6;
    const int l   = tid & 63;
    const int n   = l & 15, g = l >> 4;
    const int grp = blockIdx.x * 4 + wv;
    const int rg  = grp * 16 + n;            // global row = bp*4 + h
    const int bp  = rg >> 2, h = rg & 3;

    // weight fragments (per-lane, static for the whole kernel)
    const u32x2* wp = (const u32x2*)ws;
    const f32x4* bptr = (const f32x4*)(ws + 2048);
    s16x4 w1h[4], w1l[4], w2h[4], w2l[4];
    f32x4 b1f[4];
    #pragma unroll
    for (int t = 0; t < 4; ++t) {
        w1h[t] = __builtin_bit_cast(s16x4, wp[      t*64 + l]);
        w1l[t] = __builtin_bit_cast(s16x4, wp[256 + t*64 + l]);
        w2h[t] = __builtin_bit_cast(s16x4, wp[512 + t*64 + l]);
        w2l[t] = __builtin_bit_cast(s16x4, wp[768 + t*64 + l]);
        b1f[t] = bptr[t*64 + l];
    }

    const size_t qoff  = (size_t)rg * 16 + g * 4;
    const f32x4  qf    = *(const f32x4*)(q + qoff);
    const size_t kbase = (size_t)bp * 576 + h * 16 + g * 4;   // 9*64 per bp

    f32x4 lsum = {0.f, 0.f, 0.f, 0.f};
    f32x4 acc  = {0.f, 0.f, 0.f, 0.f};

    #pragma unroll 3
    for (int j = 0; j < 9; ++j) {
        const size_t off = kbase + (size_t)j * 64;
        f32x4 kf = *(const f32x4*)(k  + off);
        f32x4 pf = *(const f32x4*)(pe + off);
        f32x4 vf = *(const f32x4*)(v  + off);

        f32x4 x = qf - kf + pf;
        s16x4 xh, xl; split4(x, xh, xl);

        f32x4 c2 = {0.f, 0.f, 0.f, 0.f};
        #pragma unroll
        for (int t = 0; t < 4; ++t) {
            f32x4 c1 = b1f[t];
            c1 = MFMA(w1l[t], xh, c1);
            c1 = MFMA(w1h[t], xl, c1);
            c1 = MFMA(w1h[t], xh, c1);
            f32x4 hr;
            hr.x = fmaxf(c1.x, 0.f); hr.y = fmaxf(c1.y, 0.f);
            hr.z = fmaxf(c1.z, 0.f); hr.w = fmaxf(c1.w, 0.f);
            s16x4 hh, hl; split4(hr, hh, hl);
            c2 = MFMA(w2l[t], hh, c2);
            c2 = MFMA(w2h[t], hl, c2);
            c2 = MFMA(w2h[t], hh, c2);
        }

        f32x4 vp = vf + pf;
        float e0 = __expf(c2.x), e1 = __expf(c2.y);
        float e2 = __expf(c2.z), e3 = __expf(c2.w);
        lsum.x += e0; lsum.y += e1; lsum.z += e2; lsum.w += e3;
        acc.x = fmaf(e0, vp.x, acc.x); acc.y = fmaf(e1, vp.y, acc.y);
        acc.z = fmaf(e2, vp.z, acc.z); acc.w = fmaf(e3, vp.w, acc.w);
    }

    f32x4 o;
    o.x = __fdividef(acc.x, lsum.x); o.y = __fdividef(acc.y, lsum.y);
    o.z = __fdividef(acc.z, lsum.z); o.w = __fdividef(acc.w, lsum.w);
    *(f32x4*)(out + qoff) = o;
}

extern "C" void kernel_launch(void* const* d_in, const int* in_sizes, int n_in,
                              void* d_out, int out_size, void* d_ws, size_t ws_size,
                              hipStream_t stream) {
    const float* q  = (const float*)d_in[0];
    const float* k  = (const float*)d_in[1];
    const float* v  = (const float*)d_in[2];
    const float* pe = (const float*)d_in[3];
    const float* W1 = (const float*)d_in[4];
    const float* b1 = (const float*)d_in[5];
    const float* W2 = (const float*)d_in[6];
    // d_in[7] = b2: cancels in softmax over neighbors.
    float* out = (float*)d_out;
    float* ws  = (float*)d_ws;   // uses 12 KB: 8 KB bf16 frags + 4 KB b1 frags

    pack_weights<<<1, 256, 0, stream>>>(W1, b1, W2, ws);

    const int nrows  = in_sizes[0] / 16;   // (bs*num_p)*4 heads = 262144
    const int groups = nrows / 16;         // 16384 wave-groups
    const int grid   = groups / 4;         // 4 waves per 256-thread block
    subattn_mfma<<<grid, 256, 0, stream>>>(q, k, v, pe, ws, out);
}

// Round 7
// 104.442 us; speedup vs baseline: 3.6639x; 3.6639x over previous
//
#include <hip/hip_runtime.h>

typedef unsigned int uint;
typedef unsigned short ushort;
typedef __attribute__((ext_vector_type(2))) uint  u32x2;
typedef __attribute__((ext_vector_type(4))) short s16x4;
typedef __attribute__((ext_vector_type(4))) float f32x4;

#if __has_builtin(__builtin_amdgcn_mfma_f32_16x16x16bf16_1k)
#define MFMA(a,b,c) __builtin_amdgcn_mfma_f32_16x16x16bf16_1k((a),(b),(c),0,0,0)
#else
__device__ __forceinline__ f32x4 mfma_fb(s16x4 a, s16x4 b, f32x4 c){
    asm volatile("v_mfma_f32_16x16x16_bf16 %0, %1, %2, %0\n\ts_nop 7\n\ts_nop 7"
                 : "+v"(c) : "v"(a), "v"(b));
    return c;
}
#define MFMA(a,b,c) mfma_fb((a),(b),(c))
#endif

__device__ __forceinline__ uint  fbits(float f){ return __builtin_bit_cast(uint, f); }
__device__ __forceinline__ float ibits(uint u){ return __builtin_bit_cast(float, u); }

// truncation split: x ~= hi + lo, both bf16 (error ~2^-17 rel; lo*lo dropped)
__device__ __forceinline__ void split4(f32x4 x, s16x4& hi, s16x4& lo){
    uint b0=fbits(x.x), b1=fbits(x.y), b2=fbits(x.z), b3=fbits(x.w);
    u32x2 h; h.x = (b0>>16) | (b1 & 0xFFFF0000u); h.y = (b2>>16) | (b3 & 0xFFFF0000u);
    float l0 = x.x - ibits(b0 & 0xFFFF0000u);
    float l1 = x.y - ibits(b1 & 0xFFFF0000u);
    float l2 = x.z - ibits(b2 & 0xFFFF0000u);
    float l3 = x.w - ibits(b3 & 0xFFFF0000u);
    u32x2 l; l.x = (fbits(l0)>>16) | (fbits(l1) & 0xFFFF0000u);
    l.y = (fbits(l2)>>16) | (fbits(l3) & 0xFFFF0000u);
    hi = __builtin_bit_cast(s16x4, h);
    lo = __builtin_bit_cast(s16x4, l);
}

// ---------------- weight packing into per-lane MFMA fragments ----------------
// uint2 units: [0..255] W1hi  [256..511] W1lo  [512..767] W2hi  [768..1023] W2lo
//   (index = t*64 + lane). Then floats at 2048+: b1 fragments, f32x4 per (t,lane).
__global__ void pack_weights(const float* __restrict__ W1, const float* __restrict__ b1,
                             const float* __restrict__ W2, float* __restrict__ ws)
{
    const int e = threadIdx.x;          // 256 = 4 tiles * 64 lanes
    const int t = e >> 6, l = e & 63;
    const int g = l >> 4, m = l & 15;

    float w1v[4], w2v[4];
    #pragma unroll
    for (int j = 0; j < 4; ++j) {
        w1v[j] = W1[(4*g + j)*64 + 16*t + m];
        w2v[j] = W2[(16*t + 4*g + j)*16 + m];
    }
    ushort h1[4], o1[4], h2[4], o2[4];
    #pragma unroll
    for (int j = 0; j < 4; ++j) {
        uint u1 = fbits(w1v[j]);
        ushort a = (ushort)((u1 + 0x7FFFu + ((u1>>16)&1u)) >> 16);      // RNE hi
        float  r = w1v[j] - ibits(((uint)a) << 16);
        uint ur = fbits(r);
        ushort b = (ushort)((ur + 0x7FFFu + ((ur>>16)&1u)) >> 16);      // RNE lo
        h1[j] = a; o1[j] = b;
        uint u2 = fbits(w2v[j]);
        a = (ushort)((u2 + 0x7FFFu + ((u2>>16)&1u)) >> 16);
        r = w2v[j] - ibits(((uint)a) << 16);
        ur = fbits(r);
        b = (ushort)((ur + 0x7FFFu + ((ur>>16)&1u)) >> 16);
        h2[j] = a; o2[j] = b;
    }
    u32x2* wp = (u32x2*)ws;
    u32x2 x;
    x.x = (uint)h1[0] | ((uint)h1[1] << 16); x.y = (uint)h1[2] | ((uint)h1[3] << 16);
    wp[e] = x;
    x.x = (uint)o1[0] | ((uint)o1[1] << 16); x.y = (uint)o1[2] | ((uint)o1[3] << 16);
    wp[256 + e] = x;
    x.x = (uint)h2[0] | ((uint)h2[1] << 16); x.y = (uint)h2[2] | ((uint)h2[3] << 16);
    wp[512 + e] = x;
    x.x = (uint)o2[0] | ((uint)o2[1] << 16); x.y = (uint)o2[2] | ((uint)o2[3] << 16);
    wp[768 + e] = x;

    f32x4 bb;
    bb.x = b1[16*t + 4*g + 0]; bb.y = b1[16*t + 4*g + 1];
    bb.z = b1[16*t + 4*g + 2]; bb.w = b1[16*t + 4*g + 3];
    ((f32x4*)(ws + 2048))[e] = bb;
}

// ---------------- main kernel ----------------
// One wave = 16 rows. Swapped-operand GEMMs make layer-1's C-fragment exactly
// layer-2's B-fragment (zero cross-lane movement). hi/lo bf16 split keeps fp32
// accuracy.
// ROUND 7: back to waves_per_eu(4,4) (round 6's (8,8) forced VGPR=32 -> 506 MB
// spill traffic). New: explicit 1-deep load pipeline (k/pe of j+1 + v of j
// issued before j's MFMA phase) and two independent c2 accumulator chains --
// uses the idle half of the 128-VGPR budget to hide memory latency that
// capped round 5 at <41% on every pipe.
__global__ __launch_bounds__(256) __attribute__((amdgpu_waves_per_eu(4, 4)))
void subattn_mfma(const float* __restrict__ q, const float* __restrict__ k,
                  const float* __restrict__ v, const float* __restrict__ pe,
                  const float* __restrict__ ws, float* __restrict__ out)
{
    const int tid = threadIdx.x;
    const int wv  = tid >> 6;
    const int l   = tid & 63;
    const int n   = l & 15, g = l >> 4;
    const int grp = blockIdx.x * 4 + wv;
    const int rg  = grp * 16 + n;            // global row = bp*4 + h
    const int bp  = rg >> 2, h = rg & 3;

    // weight fragments (per-lane, static for the whole kernel): 48 VGPRs
    const u32x2* wp = (const u32x2*)ws;
    const f32x4* bptr = (const f32x4*)(ws + 2048);
    s16x4 w1h[4], w1l[4], w2h[4], w2l[4];
    f32x4 b1f[4];
    #pragma unroll
    for (int t = 0; t < 4; ++t) {
        w1h[t] = __builtin_bit_cast(s16x4, wp[      t*64 + l]);
        w1l[t] = __builtin_bit_cast(s16x4, wp[256 + t*64 + l]);
        w2h[t] = __builtin_bit_cast(s16x4, wp[512 + t*64 + l]);
        w2l[t] = __builtin_bit_cast(s16x4, wp[768 + t*64 + l]);
        b1f[t] = bptr[t*64 + l];
    }

    const size_t qoff  = (size_t)rg * 16 + g * 4;
    const f32x4  qf    = *(const f32x4*)(q + qoff);
    const size_t kbase = (size_t)bp * 576 + h * 16 + g * 4;   // 9*64 per bp

    f32x4 lsum = {0.f, 0.f, 0.f, 0.f};
    f32x4 acc  = {0.f, 0.f, 0.f, 0.f};

    // pipeline prologue: k/pe of neighbor 0
    f32x4 kf = *(const f32x4*)(k  + kbase);
    f32x4 pf = *(const f32x4*)(pe + kbase);

    for (int j = 0; j < 9; ++j) {            // dynamic loop: no unroll-hoisting
        // issue next-neighbor k/pe and current-neighbor v FIRST; their latency
        // hides under this iteration's MFMA phase (+3 other resident waves)
        f32x4 kn, pn;
        if (j < 8) {
            const size_t noff = kbase + (size_t)(j + 1) * 64;
            kn = *(const f32x4*)(k  + noff);
            pn = *(const f32x4*)(pe + noff);
        }
        const f32x4 vf = *(const f32x4*)(v + kbase + (size_t)j * 64);

        f32x4 x = qf - kf + pf;
        s16x4 xh, xl; split4(x, xh, xl);

        // two independent accumulator chains (tiles 0,2 -> c2a; 1,3 -> c2b),
        // pairwise-interleaved so the scheduler sees 2 parallel MFMA streams
        f32x4 c2a = {0.f, 0.f, 0.f, 0.f};
        f32x4 c2b = {0.f, 0.f, 0.f, 0.f};
        #pragma unroll
        for (int tp = 0; tp < 2; ++tp) {
            const int t0 = tp * 2, t1 = tp * 2 + 1;
            f32x4 c1a = b1f[t0], c1b = b1f[t1];
            c1a = MFMA(w1l[t0], xh, c1a);  c1b = MFMA(w1l[t1], xh, c1b);
            c1a = MFMA(w1h[t0], xl, c1a);  c1b = MFMA(w1h[t1], xl, c1b);
            c1a = MFMA(w1h[t0], xh, c1a);  c1b = MFMA(w1h[t1], xh, c1b);
            f32x4 ra, rb;
            ra.x = fmaxf(c1a.x, 0.f); ra.y = fmaxf(c1a.y, 0.f);
            ra.z = fmaxf(c1a.z, 0.f); ra.w = fmaxf(c1a.w, 0.f);
            rb.x = fmaxf(c1b.x, 0.f); rb.y = fmaxf(c1b.y, 0.f);
            rb.z = fmaxf(c1b.z, 0.f); rb.w = fmaxf(c1b.w, 0.f);
            s16x4 hah, hal, hbh, hbl;
            split4(ra, hah, hal);
            split4(rb, hbh, hbl);
            c2a = MFMA(w2l[t0], hah, c2a);  c2b = MFMA(w2l[t1], hbh, c2b);
            c2a = MFMA(w2h[t0], hal, c2a);  c2b = MFMA(w2h[t1], hbl, c2b);
            c2a = MFMA(w2h[t0], hah, c2a);  c2b = MFMA(w2h[t1], hbh, c2b);
        }
        const f32x4 c2 = c2a + c2b;

        const f32x4 vp = vf + pf;
        float e0 = __expf(c2.x), e1 = __expf(c2.y);
        float e2 = __expf(c2.z), e3 = __expf(c2.w);
        lsum.x += e0; lsum.y += e1; lsum.z += e2; lsum.w += e3;
        acc.x = fmaf(e0, vp.x, acc.x); acc.y = fmaf(e1, vp.y, acc.y);
        acc.z = fmaf(e2, vp.z, acc.z); acc.w = fmaf(e3, vp.w, acc.w);

        kf = kn; pf = pn;                    // rotate pipeline
    }

    f32x4 o;
    o.x = __fdividef(acc.x, lsum.x); o.y = __fdividef(acc.y, lsum.y);
    o.z = __fdividef(acc.z, lsum.z); o.w = __fdividef(acc.w, lsum.w);
    *(f32x4*)(out + qoff) = o;
}

extern "C" void kernel_launch(void* const* d_in, const int* in_sizes, int n_in,
                              void* d_out, int out_size, void* d_ws, size_t ws_size,
                              hipStream_t stream) {
    const float* q  = (const float*)d_in[0];
    const float* k  = (const float*)d_in[1];
    const float* v  = (const float*)d_in[2];
    const float* pe = (const float*)d_in[3];
    const float* W1 = (const float*)d_in[4];
    const float* b1 = (const float*)d_in[5];
    const float* W2 = (const float*)d_in[6];
    // d_in[7] = b2: cancels in softmax over neighbors.
    float* out = (float*)d_out;
    float* ws  = (float*)d_ws;   // uses 12 KB: 8 KB bf16 frags + 4 KB b1 frags

    pack_weights<<<1, 256, 0, stream>>>(W1, b1, W2, ws);

    const int nrows  = in_sizes[0] / 16;   // (bs*num_p)*4 heads = 262144
    const int groups = nrows / 16;         // 16384 wave-groups
    const int grid   = groups / 4;         // 4 waves per 256-thread block
    subattn_mfma<<<grid, 256, 0, stream>>>(q, k, v, pe, ws, out);
}

// Round 9
// 98.370 us; speedup vs baseline: 3.8901x; 1.0617x over previous
//
#include <hip/hip_runtime.h>

typedef unsigned int uint;
typedef unsigned short ushort;
typedef __attribute__((ext_vector_type(4))) uint   u32x4;
typedef __attribute__((ext_vector_type(8))) short  short8;
typedef __attribute__((ext_vector_type(8))) __bf16 bf16x8;
typedef __attribute__((ext_vector_type(4))) float  f32x4;

// Device pass: real gfx950 builtin (signature takes v8 __bf16 operands).
// Host pass: builtin not visible -> asm fallback body (parsed, never codegen'd).
__device__ __forceinline__ f32x4 mfma32(short8 a, short8 b, f32x4 c){
#if __has_builtin(__builtin_amdgcn_mfma_f32_16x16x32_bf16)
    return __builtin_amdgcn_mfma_f32_16x16x32_bf16(
        __builtin_bit_cast(bf16x8, a), __builtin_bit_cast(bf16x8, b), c, 0, 0, 0);
#else
    asm volatile("v_mfma_f32_16x16x32_bf16 %0, %1, %2, %0\n\ts_nop 7\n\ts_nop 7"
                 : "+v"(c) : "v"(a), "v"(b));
    return c;
#endif
}

__device__ __forceinline__ uint  fbits(float f){ return __builtin_bit_cast(uint, f); }
__device__ __forceinline__ float ibits(uint u){ return __builtin_bit_cast(float, u); }
__device__ __forceinline__ ushort rne_bf16(float f){
    uint u = fbits(f);
    return (ushort)((u + 0x7FFFu + ((u >> 16) & 1u)) >> 16);
}
// packed 2xf32 -> 2xbf16 (low = a, high = b); single HW op on gfx950
__device__ __forceinline__ uint cvtpk(float a, float b){
    uint r;
    asm("v_cvt_pk_bf16_f32 %0, %1, %2" : "=v"(r) : "v"(a), "v"(b));
    return r;
}

// ---------------- weight packing into per-lane K=32 MFMA fragments ----------------
// Slot convention (valid because A and B share the same (g,e)->k map, so the HW
// k-permutation cancels): slot (g=lane>>4, e=0..7) of the K=32 operand.
//  A1[t]: slot e -> channel c = 4g+(e&3); part = (e<4) ? hi : lo of W1[c][16t+m]
//  A2[p]: slot e -> hidden  = 16*(2p+(e>>2)) + 4g + (e&3); value = bf16(W2[hid][m])
//  b1f[t]: f32x4 = b1[16t+4g+r]  (C-in bias for layer 1; bias is per-row so
//          lane's reg r needs b1 at row 4g+r of tile t)
// ws u32 layout: [0..1023] A1 (t*64+l)*4+reg ; [1024..1535] A2 (p*64+l)*4+reg ;
//                [1536..2559] b1f as f32 (t*64+l)*4+r
__global__ void pack_weights(const float* __restrict__ W1, const float* __restrict__ b1,
                             const float* __restrict__ W2, float* __restrict__ ws)
{
    const int e4 = threadIdx.x;         // 256 = 4 tiles * 64 lanes
    const int t = e4 >> 6, l = e4 & 63;
    const int g = l >> 4, m = l & 15;
    uint* wsu = (uint*)ws;

    // A1 tile t: hi part in K-half 0 (e=0..3), lo residual in K-half 1 (e=4..7)
    ushort el[8];
    #pragma unroll
    for (int i = 0; i < 8; ++i) {
        const int c = 4*g + (i & 3);
        const float w = W1[c * 64 + 16*t + m];   // W1 is (16,64) row-major
        const ushort hi = rne_bf16(w);
        if (i < 4) el[i] = hi;
        else       el[i] = rne_bf16(w - ibits(((uint)hi) << 16));  // lo residual
    }
    #pragma unroll
    for (int r = 0; r < 4; ++r)
        wsu[(t*64 + l)*4 + r] = (uint)el[2*r] | ((uint)el[2*r+1] << 16);

    // A2 pair p (only t<2): two 16-hidden tiles per K=32
    if (t < 2) {
        const int p = t;
        ushort e2[8];
        #pragma unroll
        for (int i = 0; i < 8; ++i) {
            const int hid = 16*(2*p + (i >> 2)) + 4*g + (i & 3);
            e2[i] = rne_bf16(W2[hid * 16 + m]);  // W2 is (64,16) row-major
        }
        #pragma unroll
        for (int r = 0; r < 4; ++r)
            wsu[1024 + (p*64 + l)*4 + r] = (uint)e2[2*r] | ((uint)e2[2*r+1] << 16);
    }

    // b1 fragment
    #pragma unroll
    for (int r = 0; r < 4; ++r)
        ws[1536 + (t*64 + l)*4 + r] = b1[16*t + 4*g + r];
}

// ---------------- main kernel ----------------
// One wave = 16 rows; lane (n=l&15, g=l>>4) owns row n, channel window 4g..4g+3.
// Per neighbor: 4 independent K=32 MFMAs for layer 1 (W1 hi+lo packed into the
// two K-halves, x_hi duplicated), relu+cvt_pk, then 2 chained K=32 MFMAs for
// layer 2 whose B-fragment is exactly the packed layer-1 output -- zero
// cross-lane movement anywhere. 6 MFMAs/neighbor vs round-7's 24.
// waves_per_eu(4,4) retained: proven safe (r5/r7); (8,8) forced VGPR=32 and
// 506 MB of spill traffic (r6).
__global__ __launch_bounds__(256) __attribute__((amdgpu_waves_per_eu(4, 4)))
void subattn_mfma(const float* __restrict__ q, const float* __restrict__ k,
                  const float* __restrict__ v, const float* __restrict__ pe,
                  const float* __restrict__ ws, float* __restrict__ out)
{
    const int tid = threadIdx.x;
    const int wv  = tid >> 6;
    const int l   = tid & 63;
    const int n   = l & 15, g = l >> 4;
    const int grp = blockIdx.x * 4 + wv;
    const int rg  = grp * 16 + n;            // global row = bp*4 + h
    const int bp  = rg >> 2, h = rg & 3;

    // weight fragments: A1 16 + A2 8 + b1f 16 = 40 VGPRs persistent
    const u32x4* a1p = (const u32x4*)ws;
    const u32x4* a2p = (const u32x4*)(ws + 1024);
    const f32x4* bfp = (const f32x4*)(ws + 1536);
    short8 a1[4], a2[2];
    f32x4  b1f[4];
    #pragma unroll
    for (int t = 0; t < 4; ++t) {
        a1[t]  = __builtin_bit_cast(short8, a1p[t*64 + l]);
        b1f[t] = bfp[t*64 + l];
    }
    #pragma unroll
    for (int p = 0; p < 2; ++p) a2[p] = __builtin_bit_cast(short8, a2p[p*64 + l]);

    const size_t qoff  = (size_t)rg * 16 + g * 4;
    const f32x4  qf    = *(const f32x4*)(q + qoff);
    const size_t kbase = (size_t)bp * 576 + h * 16 + g * 4;   // 9*64 per bp

    f32x4 lsum = {0.f, 0.f, 0.f, 0.f};
    f32x4 acc  = {0.f, 0.f, 0.f, 0.f};

    // 1-deep pipeline: k/pe of neighbor 0
    f32x4 kf = *(const f32x4*)(k  + kbase);
    f32x4 pf = *(const f32x4*)(pe + kbase);

    for (int j = 0; j < 9; ++j) {
        f32x4 kn, pn;
        if (j < 8) {
            const size_t noff = kbase + (size_t)(j + 1) * 64;
            kn = *(const f32x4*)(k  + noff);
            pn = *(const f32x4*)(pe + noff);
        }
        const f32x4 vf = *(const f32x4*)(v + kbase + (size_t)j * 64);

        const f32x4 x = qf - kf + pf;
        const uint xp0 = cvtpk(x.x, x.y);
        const uint xp1 = cvtpk(x.z, x.w);
        const u32x4 bxu = {xp0, xp1, xp0, xp1};        // [x_hi | x_hi] K-halves
        const short8 bx = __builtin_bit_cast(short8, bxu);

        // layer 1: 4 independent MFMAs, bias as C-in
        f32x4 c1_0 = mfma32(a1[0], bx, b1f[0]);
        f32x4 c1_1 = mfma32(a1[1], bx, b1f[1]);
        f32x4 c1_2 = mfma32(a1[2], bx, b1f[2]);
        f32x4 c1_3 = mfma32(a1[3], bx, b1f[3]);

        // relu + pack to bf16: ph[t] = h[n][16t+4g+{0,1,2,3}]
        uint ph[4][2];
        {
            f32x4 c1s[4] = {c1_0, c1_1, c1_2, c1_3};
            #pragma unroll
            for (int t = 0; t < 4; ++t) {
                const float r0 = fmaxf(c1s[t].x, 0.f), r1 = fmaxf(c1s[t].y, 0.f);
                const float r2 = fmaxf(c1s[t].z, 0.f), r3 = fmaxf(c1s[t].w, 0.f);
                ph[t][0] = cvtpk(r0, r1);
                ph[t][1] = cvtpk(r2, r3);
            }
        }

        // layer 2: B-fragment = concatenated layer-1 outputs (no shuffles)
        const u32x4 bh0u = {ph[0][0], ph[0][1], ph[1][0], ph[1][1]};
        const u32x4 bh1u = {ph[2][0], ph[2][1], ph[3][0], ph[3][1]};
        f32x4 c2 = {0.f, 0.f, 0.f, 0.f};
        c2 = mfma32(a2[0], __builtin_bit_cast(short8, bh0u), c2);
        c2 = mfma32(a2[1], __builtin_bit_cast(short8, bh1u), c2);
        // b2 omitted: softmax over neighbors is shift-invariant in b2.

        const f32x4 vp = vf + pf;
        const float e0 = __expf(c2.x), e1 = __expf(c2.y);
        const float e2 = __expf(c2.z), e3 = __expf(c2.w);
        lsum.x += e0; lsum.y += e1; lsum.z += e2; lsum.w += e3;
        acc.x = fmaf(e0, vp.x, acc.x); acc.y = fmaf(e1, vp.y, acc.y);
        acc.z = fmaf(e2, vp.z, acc.z); acc.w = fmaf(e3, vp.w, acc.w);

        kf = kn; pf = pn;
    }

    f32x4 o;
    o.x = __fdividef(acc.x, lsum.x); o.y = __fdividef(acc.y, lsum.y);
    o.z = __fdividef(acc.z, lsum.z); o.w = __fdividef(acc.w, lsum.w);
    *(f32x4*)(out + qoff) = o;
}

extern "C" void kernel_launch(void* const* d_in, const int* in_sizes, int n_in,
                              void* d_out, int out_size, void* d_ws, size_t ws_size,
                              hipStream_t stream) {
    const float* q  = (const float*)d_in[0];
    const float* k  = (const float*)d_in[1];
    const float* v  = (const float*)d_in[2];
    const float* pe = (const float*)d_in[3];
    const float* W1 = (const float*)d_in[4];
    const float* b1 = (const float*)d_in[5];
    const float* W2 = (const float*)d_in[6];
    // d_in[7] = b2: cancels in softmax over neighbors.
    float* out = (float*)d_out;
    float* ws  = (float*)d_ws;   // uses 2560 * 4 B = 10 KB

    pack_weights<<<1, 256, 0, stream>>>(W1, b1, W2, ws);

    const int nrows  = in_sizes[0] / 16;   // (bs*num_p)*4 heads = 262144
    const int groups = nrows / 16;         // 16384 wave-groups
    const int grid   = groups / 4;         // 4 waves per 256-thread block
    subattn_mfma<<<grid, 256, 0, stream>>>(q, k, v, pe, ws, out);
}

// Round 10
// 97.254 us; speedup vs baseline: 3.9347x; 1.0115x over previous
//
#include <hip/hip_runtime.h>

typedef unsigned int uint;
typedef unsigned short ushort;
typedef __attribute__((ext_vector_type(4))) uint   u32x4;
typedef __attribute__((ext_vector_type(8))) short  short8;
typedef __attribute__((ext_vector_type(8))) __bf16 bf16x8;
typedef __attribute__((ext_vector_type(4))) float  f32x4;

// Device pass: real gfx950 builtin. Host pass: inert asm fallback (never codegen'd).
__device__ __forceinline__ f32x4 mfma32(short8 a, short8 b, f32x4 c){
#if __has_builtin(__builtin_amdgcn_mfma_f32_16x16x32_bf16)
    return __builtin_amdgcn_mfma_f32_16x16x32_bf16(
        __builtin_bit_cast(bf16x8, a), __builtin_bit_cast(bf16x8, b), c, 0, 0, 0);
#else
    asm volatile("v_mfma_f32_16x16x32_bf16 %0, %1, %2, %0\n\ts_nop 7\n\ts_nop 7"
                 : "+v"(c) : "v"(a), "v"(b));
    return c;
#endif
}

__device__ __forceinline__ uint  fbits(float f){ return __builtin_bit_cast(uint, f); }
__device__ __forceinline__ float ibits(uint u){ return __builtin_bit_cast(float, u); }
__device__ __forceinline__ ushort rne_bf16(float f){
    uint u = fbits(f);
    return (ushort)((u + 0x7FFFu + ((u >> 16) & 1u)) >> 16);
}
// packed 2xf32 -> 2xbf16 (low = a, high = b); single HW op on gfx950
__device__ __forceinline__ uint cvtpk(float a, float b){
    uint r;
    asm("v_cvt_pk_bf16_f32 %0, %1, %2" : "=v"(r) : "v"(a), "v"(b));
    return r;
}

// ---------------- weight packing into per-lane K=32 MFMA fragments ----------------
// Slot convention (valid because A and B share the same (g,e)->k map, so the HW
// k-permutation cancels): slot (g=lane>>4, e=0..7) of the K=32 operand.
//  A1[t]: slot e -> channel c = 4g+(e&3); part = (e<4) ? hi : lo of W1[c][16t+m]
//  A2[p]: slot e -> hidden  = 16*(2p+(e>>2)) + 4g + (e&3); value = bf16(W2[hid][m])
//  b1f[t]: f32x4 = b1[16t+4g+r]  (C-in bias for layer 1)
// ws u32 layout: [0..1023] A1 (t*64+l)*4+reg ; [1024..1535] A2 (p*64+l)*4+reg ;
//                [1536..2559] b1f as f32 (t*64+l)*4+r
__global__ void pack_weights(const float* __restrict__ W1, const float* __restrict__ b1,
                             const float* __restrict__ W2, float* __restrict__ ws)
{
    const int e4 = threadIdx.x;         // 256 = 4 tiles * 64 lanes
    const int t = e4 >> 6, l = e4 & 63;
    const int g = l >> 4, m = l & 15;
    uint* wsu = (uint*)ws;

    // A1 tile t: hi part in K-half 0 (e=0..3), lo residual in K-half 1 (e=4..7)
    ushort el[8];
    #pragma unroll
    for (int i = 0; i < 8; ++i) {
        const int c = 4*g + (i & 3);
        const float w = W1[c * 64 + 16*t + m];   // W1 is (16,64) row-major
        const ushort hi = rne_bf16(w);
        if (i < 4) el[i] = hi;
        else       el[i] = rne_bf16(w - ibits(((uint)hi) << 16));  // lo residual
    }
    #pragma unroll
    for (int r = 0; r < 4; ++r)
        wsu[(t*64 + l)*4 + r] = (uint)el[2*r] | ((uint)el[2*r+1] << 16);

    // A2 pair p (only t<2): two 16-hidden tiles per K=32
    if (t < 2) {
        const int p = t;
        ushort e2[8];
        #pragma unroll
        for (int i = 0; i < 8; ++i) {
            const int hid = 16*(2*p + (i >> 2)) + 4*g + (i & 3);
            e2[i] = rne_bf16(W2[hid * 16 + m]);  // W2 is (64,16) row-major
        }
        #pragma unroll
        for (int r = 0; r < 4; ++r)
            wsu[1024 + (p*64 + l)*4 + r] = (uint)e2[2*r] | ((uint)e2[2*r+1] << 16);
    }

    // b1 fragment
    #pragma unroll
    for (int r = 0; r < 4; ++r)
        ws[1536 + (t*64 + l)*4 + r] = b1[16*t + 4*g + r];
}

// ---------------- main kernel ----------------
// One wave = 16 rows; lane (n=l&15, g=l>>4) owns row n, channel window 4g..4g+3.
// ROUND 10: 3-deep rotating load pipeline. 9 neighbors fully unrolled over 3
// named register stages; each body consumes stage s then immediately re-issues
// its k/pe/v loads for neighbor j+3, keeping ~9 KB/wave in flight continuously
// (round 9 had <1 KB average -> latency-bound at 4% MFMA / 14% VALU).
// 6 MFMAs/neighbor (K=32, W1 hi+lo in the two K-halves; layer-1 C packs
// directly into layer-2 B). waves_per_eu(4,4): proven no-spill envelope.
__global__ __launch_bounds__(256) __attribute__((amdgpu_waves_per_eu(4, 4)))
void subattn_mfma(const float* __restrict__ q, const float* __restrict__ k,
                  const float* __restrict__ v, const float* __restrict__ pe,
                  const float* __restrict__ ws, float* __restrict__ out)
{
    const int tid = threadIdx.x;
    const int wv  = tid >> 6;
    const int l   = tid & 63;
    const int n   = l & 15, g = l >> 4;
    const int grp = blockIdx.x * 4 + wv;
    const int rg  = grp * 16 + n;            // global row = bp*4 + h
    const int bp  = rg >> 2, h = rg & 3;

    // weight fragments: A1 16 + A2 8 + b1f 16 = 40 VGPRs persistent
    const u32x4* a1p = (const u32x4*)ws;
    const u32x4* a2p = (const u32x4*)(ws + 1024);
    const f32x4* bfp = (const f32x4*)(ws + 1536);
    short8 a1[4], a2[2];
    f32x4  b1f[4];
    #pragma unroll
    for (int t = 0; t < 4; ++t) {
        a1[t]  = __builtin_bit_cast(short8, a1p[t*64 + l]);
        b1f[t] = bfp[t*64 + l];
    }
    #pragma unroll
    for (int p = 0; p < 2; ++p) a2[p] = __builtin_bit_cast(short8, a2p[p*64 + l]);

    const size_t qoff  = (size_t)rg * 16 + g * 4;
    const f32x4  qf    = *(const f32x4*)(q + qoff);
    const size_t kbase = (size_t)bp * 576 + h * 16 + g * 4;   // 9*64 per bp
    const float* kq = k  + kbase;
    const float* pq = pe + kbase;
    const float* vq = v  + kbase;

    f32x4 lsum = {0.f, 0.f, 0.f, 0.f};
    f32x4 acc  = {0.f, 0.f, 0.f, 0.f};

    // 3 pipeline stages, named registers (static indexing only)
    f32x4 k0, p0, v0, k1, p1, v1, k2, p2, v2;
    k0 = *(const f32x4*)(kq);        p0 = *(const f32x4*)(pq);
    v0 = *(const f32x4*)(vq);
    k1 = *(const f32x4*)(kq + 64);   p1 = *(const f32x4*)(pq + 64);
    v1 = *(const f32x4*)(vq + 64);
    k2 = *(const f32x4*)(kq + 128);  p2 = *(const f32x4*)(pq + 128);
    v2 = *(const f32x4*)(vq + 128);

    // body: consume stage (KS,PS,VS), refill it with neighbor JN (compile-time)
#define BODY(KS, PS, VS, JN)                                                   \
    {                                                                          \
        const f32x4 x   = qf - KS + PS;                                        \
        const f32x4 vpl = VS + PS;                                             \
        if ((JN) < 9) {                                                        \
            KS = *(const f32x4*)(kq + (JN) * 64);                              \
            PS = *(const f32x4*)(pq + (JN) * 64);                              \
            VS = *(const f32x4*)(vq + (JN) * 64);                              \
        }                                                                      \
        const uint xp0 = cvtpk(x.x, x.y);                                      \
        const uint xp1 = cvtpk(x.z, x.w);                                      \
        const u32x4 bxu = {xp0, xp1, xp0, xp1};                                \
        const short8 bx = __builtin_bit_cast(short8, bxu);                     \
        f32x4 c1_0 = mfma32(a1[0], bx, b1f[0]);                                \
        f32x4 c1_1 = mfma32(a1[1], bx, b1f[1]);                                \
        f32x4 c1_2 = mfma32(a1[2], bx, b1f[2]);                                \
        f32x4 c1_3 = mfma32(a1[3], bx, b1f[3]);                                \
        uint ph00, ph01, ph10, ph11, ph20, ph21, ph30, ph31;                   \
        ph00 = cvtpk(fmaxf(c1_0.x, 0.f), fmaxf(c1_0.y, 0.f));                  \
        ph01 = cvtpk(fmaxf(c1_0.z, 0.f), fmaxf(c1_0.w, 0.f));                  \
        ph10 = cvtpk(fmaxf(c1_1.x, 0.f), fmaxf(c1_1.y, 0.f));                  \
        ph11 = cvtpk(fmaxf(c1_1.z, 0.f), fmaxf(c1_1.w, 0.f));                  \
        ph20 = cvtpk(fmaxf(c1_2.x, 0.f), fmaxf(c1_2.y, 0.f));                  \
        ph21 = cvtpk(fmaxf(c1_2.z, 0.f), fmaxf(c1_2.w, 0.f));                  \
        ph30 = cvtpk(fmaxf(c1_3.x, 0.f), fmaxf(c1_3.y, 0.f));                  \
        ph31 = cvtpk(fmaxf(c1_3.z, 0.f), fmaxf(c1_3.w, 0.f));                  \
        const u32x4 bh0u = {ph00, ph01, ph10, ph11};                           \
        const u32x4 bh1u = {ph20, ph21, ph30, ph31};                           \
        f32x4 c2 = {0.f, 0.f, 0.f, 0.f};                                       \
        c2 = mfma32(a2[0], __builtin_bit_cast(short8, bh0u), c2);              \
        c2 = mfma32(a2[1], __builtin_bit_cast(short8, bh1u), c2);              \
        f32x4 ev;                                                              \
        ev.x = __expf(c2.x); ev.y = __expf(c2.y);                              \
        ev.z = __expf(c2.z); ev.w = __expf(c2.w);                              \
        lsum += ev;                                                            \
        acc  += ev * vpl;                                                      \
    }

    BODY(k0, p0, v0, 3)
    BODY(k1, p1, v1, 4)
    BODY(k2, p2, v2, 5)
    BODY(k0, p0, v0, 6)
    BODY(k1, p1, v1, 7)
    BODY(k2, p2, v2, 8)
    BODY(k0, p0, v0, 9)
    BODY(k1, p1, v1, 9)
    BODY(k2, p2, v2, 9)
#undef BODY

    f32x4 o;
    o.x = __fdividef(acc.x, lsum.x); o.y = __fdividef(acc.y, lsum.y);
    o.z = __fdividef(acc.z, lsum.z); o.w = __fdividef(acc.w, lsum.w);
    *(f32x4*)(out + qoff) = o;
}

extern "C" void kernel_launch(void* const* d_in, const int* in_sizes, int n_in,
                              void* d_out, int out_size, void* d_ws, size_t ws_size,
                              hipStream_t stream) {
    const float* q  = (const float*)d_in[0];
    const float* k  = (const float*)d_in[1];
    const float* v  = (const float*)d_in[2];
    const float* pe = (const float*)d_in[3];
    const float* W1 = (const float*)d_in[4];
    const float* b1 = (const float*)d_in[5];
    const float* W2 = (const float*)d_in[6];
    // d_in[7] = b2: cancels in softmax over neighbors.
    float* out = (float*)d_out;
    float* ws  = (float*)d_ws;   // uses 2560 * 4 B = 10 KB

    pack_weights<<<1, 256, 0, stream>>>(W1, b1, W2, ws);

    const int nrows  = in_sizes[0] / 16;   // (bs*num_p)*4 heads = 262144
    const int groups = nrows / 16;         // 16384 wave-groups
    const int grid   = groups / 4;         // 4 waves per 256-thread block
    subattn_mfma<<<grid, 256, 0, stream>>>(q, k, v, pe, ws, out);
}